// Round 4
// baseline (237.315 us; speedup 1.0000x reference)
//
#include <hip/hip_runtime.h>
#include <cstdint>

// ---------------------------------------------------------------------------
// MXFP linear w/ MSD(NAF) truncation.
//
// Reduction: x_q = sgn*mx*2^(ex-3), w_q = sgn*mw*2^(ew-3), mx,mw in [8,15].
// trunc(prod, eff) == sgn * R_q(2*mx*mw, clamp(eff,0,10)) * 2^(ex+ew-7)
// where R_q = NAF truncation of q=2p: s=3p, c=s^p, np=s&c, nn=p&c,
// drop = max(width(c)-effc, 0), r = (np&keep)-(nn&keep), keep=-1<<drop.
// Scales fold exactly: fxs = sgn_x*x_s*2^ex, fws = sgn_w*w_s*2^(ew-7);
// contribution = (float)r * fxs * fws, accumulated over K, + bias.
// eff = 14 - (e_max(n,o) - floor(lx(n,b)+lw(o,b))) - d(n,b,i).
//
// R2 change: w loads were wave-uniform scalar s_loads (out-of-order SMEM ->
// lgkmcnt(0) full drain per use -> VALUBusy 23%). Now: 256-thread blocks
// stage the 16-out x 32-k wB tile into LDS (coalesced uint4 vector loads),
// inner loop reads via ds_read_b128 broadcast (in-order, pipelineable).
// ---------------------------------------------------------------------------

#define NN 128
#define KF 1024
#define OF 512
#define NB 32

__device__ __forceinline__ float quant_elem(float xn) {
    float a = fabsf(xn);
    if (!(a > 0.f)) return 0.f;
    float e = floorf(log2f(fmaxf(a, 1e-45f)));
    float step = exp2f(e - 3.f);
    return rintf(xn / step) * step;   // rintf = round-half-even, matches jnp.round
}

// blocks [0,512): x-quant.  [512,2560): w-quant.  [2560,2816): out = bias.
__global__ __launch_bounds__(256) void prep_kernel(
    const float* __restrict__ x, const float* __restrict__ w,
    const float* __restrict__ bias, float* __restrict__ out,
    uint2* __restrict__ xaT, uint2* __restrict__ wB,
    float* __restrict__ lxT, float* __restrict__ lw) {
  int bid = blockIdx.x;
  if (bid < 512) {
    int eid = bid * 256 + (int)threadIdx.x;      // 0..131071
    int n = eid >> 10, k = eid & 1023;
    float xv = x[eid];
    float m = fabsf(xv);
    #pragma unroll
    for (int s = 1; s < 32; s <<= 1) m = fmaxf(m, __shfl_xor(m, s, 32));
    float scale = fmaxf(m, 1e-30f);
    float xq = quant_elem(xv / scale);
    int mx = 0, ee = 0;
    if (xq != 0.f) {
      int ke; float fr = frexpf(fabsf(xq), &ke);
      mx = (int)rintf(fr * 16.f);                // in [8,15] (frexp normalizes 16->8)
      ee = ke - 1;
    }
    int e_i = mx ? ee : -1000000;
    int em = e_i;
    #pragma unroll
    for (int s = 1; s < 32; s <<= 1) em = max(em, __shfl_xor(em, s, 32));
    int d = mx ? min(em - ee, 63) : 63;          // d>=14 is always masked; clamp ok
    float fxs = mx ? copysignf(ldexpf(scale, ee), xq) : 0.f;
    xaT[k * NN + n] = make_uint2(__float_as_uint(fxs),
                                 (uint32_t)mx | ((uint32_t)d << 8));
    if ((threadIdx.x & 31) == 0) lxT[(k >> 5) * NN + n] = log2f(scale);
  } else if (bid < 2560) {
    int eid = (bid - 512) * 256 + (int)threadIdx.x;   // 0..524287
    int o = eid >> 10, k = eid & 1023;
    float wv = w[eid];
    float m = fabsf(wv);
    #pragma unroll
    for (int s = 1; s < 32; s <<= 1) m = fmaxf(m, __shfl_xor(m, s, 32));
    float scale = fmaxf(m, 1e-30f);
    float wq = quant_elem(wv / scale);
    int mw = 0, ee = 0;
    if (wq != 0.f) {
      int ke; float fr = frexpf(fabsf(wq), &ke);
      mw = (int)rintf(fr * 16.f);
      ee = ke - 1;
    }
    float fws = mw ? copysignf(ldexpf(scale, ee - 7), wq) : 0.f;
    wB[eid] = make_uint2(__float_as_uint(fws), (uint32_t)mw);
    if ((threadIdx.x & 31) == 0) lw[o * NB + (k >> 5)] = log2f(scale);
  } else {
    int gid = (bid - 2560) * 256 + (int)threadIdx.x;  // 0..65535
    out[gid] = bias[gid & (OF - 1)];
  }
}

__global__ __launch_bounds__(256) void emax_kernel(
    const float* __restrict__ lxT, const float* __restrict__ lw,
    float* __restrict__ emaxT) {
  int gid = blockIdx.x * 256 + (int)threadIdx.x;   // 65536
  int n = gid & (NN - 1), o = gid >> 7;
  float m = -1e30f;
  #pragma unroll
  for (int b = 0; b < NB; ++b)
    m = fmaxf(m, floorf(lxT[b * NN + n] + lw[o * NB + b]));
  emaxT[o * NN + n] = m;
}

// grid 2048 x 256 threads. bid: b = bid&31 (k-block), og = (bid>>5)&31
// (16 outputs), ng = bid>>10. Wave w owns outputs og*16 + w*4 .. +3.
__global__ __launch_bounds__(256, 6) void main_kernel(
    const uint2* __restrict__ xaT, const uint2* __restrict__ wB,
    const float* __restrict__ lxT, const float* __restrict__ lw,
    const float* __restrict__ emaxT, float* __restrict__ out) {
  __shared__ __align__(16) uint2 tile[16 * 32];   // 16 outs x 32 k, 4KB
  int bid = blockIdx.x;
  int b   = bid & 31;
  int og  = (bid >> 5) & 31;
  int ng  = bid >> 10;
  int tid = (int)threadIdx.x;
  int lane = tid & 63;
  int w = tid >> 6;
  int o_base = og * 16;
  int k0 = b * 32;
  int n = ng * 64 + lane;

  // stage wB tile: thread t loads 16B; 16 threads cover one 256B row.
  {
    int r = tid >> 4, c = (tid & 15) * 2;
    uint4 v = *reinterpret_cast<const uint4*>(&wB[(o_base + r) * KF + k0 + c]);
    *reinterpret_cast<uint4*>(&tile[r * 32 + c]) = v;
  }
  __syncthreads();

  int ow = o_base + w * 4;
  float lxv = lxT[b * NN + n];
  float acc[4];
  int budget[4];
  #pragma unroll
  for (int j = 0; j < 4; ++j) {
    acc[j] = 0.f;
    float em = emaxT[(ow + j) * NN + n];
    budget[j] = (int)(14.f - em + floorf(lxv + lw[(ow + j) * NB + b]));
  }

  #pragma unroll 2
  for (int kk = 0; kk < 32; kk += 2) {
    uint2 xv0 = xaT[(k0 + kk) * NN + n];
    uint2 xv1 = xaT[(k0 + kk + 1) * NN + n];
    uint4 tv[4];
    #pragma unroll
    for (int j = 0; j < 4; ++j)
      tv[j] = *reinterpret_cast<const uint4*>(&tile[(w * 4 + j) * 32 + kk]);
    #pragma unroll
    for (int u = 0; u < 2; ++u) {
      uint2 xv = u ? xv1 : xv0;
      float fxs = __uint_as_float(xv.x);
      int mx = (int)(xv.y & 255u);
      int di = (int)(xv.y >> 8);
      #pragma unroll
      for (int j = 0; j < 4; ++j) {
        unsigned wyf = u ? tv[j].z : tv[j].x;    // fws bits
        unsigned wym = u ? tv[j].w : tv[j].y;    // mw
        float fws = __uint_as_float(wyf);
        int mw = (int)wym;
        int p  = __mul24(mx, mw);                // p = mx*mw (q = 2p)
        int s3 = (p << 1) + p;                   // v_lshl_add: 3p
        unsigned c = (unsigned)(s3 ^ p);         // np | nn
        unsigned np = (unsigned)s3 & c;          // q-NAF positive digits
        unsigned nn = (unsigned)p & c;           // q-NAF negative digits
        int z = __clz(c);                        // 32 - width; __clz(0)=32
        int effc = min(max(budget[j] - di, 0), 10);
        int drop = max(32 - z - effc, 0);
        unsigned keep = 0xFFFFFFFFu << drop;
        int r = (int)(np & keep) - (int)(nn & keep);
        acc[j] = fmaf((float)r * fxs, fws, acc[j]);
      }
    }
  }
  #pragma unroll
  for (int j = 0; j < 4; ++j)
    unsafeAtomicAdd(&out[n * OF + ow + j], acc[j]);
}

extern "C" void kernel_launch(void* const* d_in, const int* in_sizes, int n_in,
                              void* d_out, int out_size, void* d_ws, size_t ws_size,
                              hipStream_t stream) {
  const float* x    = (const float*)d_in[0];
  const float* w    = (const float*)d_in[1];
  const float* bias = (const float*)d_in[2];
  float* out = (float*)d_out;
  char* ws = (char*)d_ws;
  // workspace layout (bytes): xaT 1MB | wB 4MB | lxT 16KB | lw 64KB | emaxT 256KB
  uint2* xaT   = (uint2*)(ws);
  uint2* wB    = (uint2*)(ws + 1048576);
  float* lxT   = (float*)(ws + 5242880);
  float* lw    = (float*)(ws + 5259264);
  float* emaxT = (float*)(ws + 5324800);

  prep_kernel<<<2816, 256, 0, stream>>>(x, w, bias, out, xaT, wB, lxT, lw);
  emax_kernel<<<256, 256, 0, stream>>>(lxT, lw, emaxT);
  main_kernel<<<2048, 256, 0, stream>>>(xaT, wB, lxT, lw, emaxT, out);
}

// Round 9
// 98.204 us; speedup vs baseline: 2.4166x; 2.4166x over previous
//
#include <hip/hip_runtime.h>
#include <cstdint>

// ---------------------------------------------------------------------------
// MXFP linear w/ MSD(NAF) truncation — round 5 (4th resubmit; broker timeouts).
//
// Math (validated rounds 1/2/4, absmax 2^-7):
//   x_q = sgn*mx*2^(ex-3), w_q = sgn*mw*2^(ew-3), mx,mw in [0,8..15].
//   trunc(prod,eff) = sgn * R(2*mx*mw, clamp(eff,0,10)) * 2^(ex+ew-7)
//   R = NAF trunc: p=mx*mw, s3=3p, c=s3^p, wd=32-clz(c),
//       drop=clamp(wd-eff,0,wd), keep=-1<<drop, kc=keep&c,
//       r=(s3&kc)-(p&kc);  contribution = r * fxs * fws.
//   fxs=sgn*xs*2^ex, fws=sgn*ws*2^(ew-7) (exact pow2 folds).
//   eff = budget - di;  budget = 14 - emax(n,o) + floor(lx_b+lw_b);
//   u = wd - eff = wd + di + (-budget) -> v_add3; drop = med3(u,0,wd).
//
// R5 changes vs R4 (dur 175us, VALUBusy 17.5%, VALU-issue ~31us both rounds
// => latency-bound, zero prefetch distance at VGPR=24; atomics 65MB writes):
//  1. explicit even/odd register double-buffer: prefetch next group's
//     global dwordx4 + 4x ds_read_b128 before computing current 8 products.
//  2. K-split 16, partials to ws (plain stores), reduce kernel adds bias —
//     no atomics. ws use 9.6MB (flagged assumption ws_size >= 10MB).
//  3. xaP packs 2 k-elements per uint4 (half the global loads); 15-op chain
//     (add3+med3); branch-free bit-trick prep (no libm in element path).
// ---------------------------------------------------------------------------

#define NN 128
#define KF 1024
#define OF 512
#define NB 32
#define KS 16           // K-split: 16 chunks x 64 k (2 blocks of 32)

// ws layout (16B-aligned offsets):
//   xaP   @ 0        1 MB   (512 kp x 128 n x 16B; 2 k-elems per uint4)
//   wB    @ 1048576  4 MB   (512 o x 1024 k x 8B: fws bits, mw)
//   lxT   @ 5242880  16 KB  (32 b x 128 n)
//   lw    @ 5259264  64 KB  (512 o x 32 b)
//   emaxT @ 5324800  256 KB (512 o x 128 n)
//   part  @ 5580800  4 MB   (16 s x 512 o x 128 n f32)

__global__ __launch_bounds__(256) void prep_kernel(
    const float* __restrict__ x, const float* __restrict__ w,
    uint2* __restrict__ xaP2, uint2* __restrict__ wB,
    float* __restrict__ lxT, float* __restrict__ lw) {
  int bid = blockIdx.x;
  int tid = (int)threadIdx.x;
  bool is_x = bid < 512;
  int eid = is_x ? bid * 256 + tid : (bid - 512) * 256 + tid;
  float v = is_x ? x[eid] : w[eid];
  float a = fabsf(v);
  float m = a;
  #pragma unroll
  for (int s = 1; s < 32; s <<= 1) m = fmaxf(m, __shfl_xor(m, s, 32));
  float scale = fmaxf(m, 1e-30f);
  float xn = v / scale;                       // IEEE-exact division
  unsigned nb_ = __float_as_uint(xn);
  unsigned ab = nb_ & 0x7fffffffu;
  bool zz = ab < 0x00800000u;                 // zero (subnormal: impossible w/ data)
  int e = (int)(ab >> 23) - 127;
  // mantissa in [1,2) exactly; mi = round-half-even(mant*8) in [8,16]
  float am = __uint_as_float((ab & 0x007fffffu) | 0x3f800000u);
  int mi = (int)rintf(am * 8.0f);
  if (mi == 16) { mi = 8; ++e; }              // renormalize (matches ref log2 of xq)
  if (zz) mi = 0;
  unsigned sgn = nb_ & 0x80000000u;
  unsigned sb = __float_as_uint(scale);
  if (is_x) {
    int ei = zz ? -1000000 : e;
    int em = ei;
    #pragma unroll
    for (int s = 1; s < 32; s <<= 1) em = max(em, __shfl_xor(em, s, 32));
    int di = zz ? 63 : min(em - e, 63);
    unsigned fb = zz ? 0u : ((sb + (((unsigned)e) << 23)) | sgn);
    unsigned meta = (unsigned)mi | ((unsigned)di << 8);
    int k = eid & 1023, n = eid >> 10;
    // packed pair layout: uint4 xaP[kp*128+n] = (fxs0,meta0,fxs1,meta1)
    xaP2[((k >> 1) * NN + n) * 2 + (k & 1)] = make_uint2(fb, meta);
    if ((tid & 31) == 0) lxT[(k >> 5) * NN + n] = log2f(scale);
  } else {
    unsigned fb = zz ? 0u : ((sb + (((unsigned)(e - 7)) << 23)) | sgn);
    wB[eid] = make_uint2(fb, (unsigned)mi);
    int o = eid >> 10, k = eid & 1023;
    if ((tid & 31) == 0) lw[o * NB + (k >> 5)] = log2f(scale);
  }
}

__global__ __launch_bounds__(256) void emax_kernel(
    const float* __restrict__ lxT, const float* __restrict__ lw,
    float* __restrict__ emaxT) {
  int gid = blockIdx.x * 256 + (int)threadIdx.x;   // 65536
  int n = gid & (NN - 1), o = gid >> 7;
  float m = -1e30f;
  #pragma unroll
  for (int b = 0; b < NB; ++b)
    m = fmaxf(m, floorf(lxT[b * NN + n] + lw[o * NB + b]));
  emaxT[o * NN + n] = m;
}

// one product: ~15 VALU ops
__device__ __forceinline__ void prod_acc(int mx, int di, float fxs,
                                         unsigned fwbits, int mw, int nb,
                                         float& acc) {
  int p  = __mul24(mx, mw);                 // <= 225
  int s3 = (p << 1) + p;                    // 3p (v_lshl_add)
  int cx = s3 ^ p;                          // NAF digit positions of q=2p
  int wd = 32 - __clz(cx);                  // width; cx==0 -> 0
  int u  = wd + di + nb;                    // v_add3 (nb = -budget)
  int drop = min(max(u, 0), wd);            // v_med3_i32
  unsigned keep = 0xFFFFFFFFu << drop;
  unsigned kc = keep & (unsigned)cx;
  int r = (int)((unsigned)s3 & kc) - (int)((unsigned)p & kc);
  acc = fmaf((float)r * fxs, __uint_as_float(fwbits), acc);
}

// grid 1024 = s(16 K-chunks) x og(32) x ng(2); 256 thr; wave w4 owns 4 outs.
__global__ __launch_bounds__(256, 4) void main_kernel(
    const uint4* __restrict__ xaP, const uint2* __restrict__ wB,
    const float* __restrict__ lxT, const float* __restrict__ lw,
    const float* __restrict__ emaxT, float* __restrict__ part) {
  __shared__ __align__(16) uint2 tile[16 * 64 + 2];  // +pad for g=32 prefetch
  int bid = blockIdx.x;
  int s   = bid & 15;
  int og  = (bid >> 4) & 31;
  int ng  = bid >> 9;
  int tid = (int)threadIdx.x, lane = tid & 63, w4 = tid >> 6;
  int o_base = og * 16;
  int k0 = s * 64;
  int n = ng * 64 + lane;
  int b0 = s * 2;

  // stage 16 outs x 64 k of wB (8KB): 16 threads/row x 2 uint4 each
  {
    int r = tid >> 4, c = tid & 15;
    const uint4* src = reinterpret_cast<const uint4*>(&wB[(o_base + r) * KF + k0]);
    uint4* dst = reinterpret_cast<uint4*>(&tile[r * 64]);
    dst[c] = src[c];
    dst[c + 16] = src[c + 16];
  }

  int ow = o_base + w4 * 4;
  float lx0 = lxT[b0 * NN + n];
  float lx1 = lxT[(b0 + 1) * NN + n];
  int nbA[4], nbB[4];
  #pragma unroll
  for (int j = 0; j < 4; ++j) {
    float em = emaxT[(ow + j) * NN + n];
    nbA[j] = -(int)(14.0f - em + floorf(lx0 + lw[(ow + j) * NB + b0]));
    nbB[j] = -(int)(14.0f - em + floorf(lx1 + lw[(ow + j) * NB + b0 + 1]));
  }
  __syncthreads();

  const uint4* xaRow = &xaP[(size_t)(k0 >> 1) * NN + n];
#define LDT(j, g) (*reinterpret_cast<const uint4*>(&tile[(w4 * 4 + (j)) * 64 + 2 * (g)]))
  float acc0 = 0.f, acc1 = 0.f, acc2 = 0.f, acc3 = 0.f;

#define COMPUTE(gv, xv, t0, t1, t2, t3)                                    \
  {                                                                        \
    int mx0 = (int)(xv.y & 255u), di0 = (int)(xv.y >> 8);                  \
    int mx1 = (int)(xv.w & 255u), di1 = (int)(xv.w >> 8);                  \
    float fx0 = __uint_as_float(xv.x), fx1 = __uint_as_float(xv.z);        \
    int nb0 = (gv) < 16 ? nbA[0] : nbB[0];                                 \
    int nb1 = (gv) < 16 ? nbA[1] : nbB[1];                                 \
    int nb2 = (gv) < 16 ? nbA[2] : nbB[2];                                 \
    int nb3 = (gv) < 16 ? nbA[3] : nbB[3];                                 \
    prod_acc(mx0, di0, fx0, t0.x, (int)t0.y, nb0, acc0);                   \
    prod_acc(mx1, di1, fx1, t0.z, (int)t0.w, nb0, acc0);                   \
    prod_acc(mx0, di0, fx0, t1.x, (int)t1.y, nb1, acc1);                   \
    prod_acc(mx1, di1, fx1, t1.z, (int)t1.w, nb1, acc1);                   \
    prod_acc(mx0, di0, fx0, t2.x, (int)t2.y, nb2, acc2);                   \
    prod_acc(mx1, di1, fx1, t2.z, (int)t2.w, nb2, acc2);                   \
    prod_acc(mx0, di0, fx0, t3.x, (int)t3.y, nb3, acc3);                   \
    prod_acc(mx1, di1, fx1, t3.z, (int)t3.w, nb3, acc3);                   \
  }

  // prologue: group 0 into the A buffer
  uint4 xa_ = xaRow[0];
  uint4 ta0 = LDT(0, 0), ta1 = LDT(1, 0), ta2 = LDT(2, 0), ta3 = LDT(3, 0);

  #pragma unroll 1
  for (int g2 = 0; g2 < 16; ++g2) {
    int gb = 2 * g2 + 1;
    // prefetch odd group into B
    uint4 xb_ = xaRow[(size_t)gb * NN];
    uint4 tb0 = LDT(0, gb), tb1 = LDT(1, gb), tb2 = LDT(2, gb), tb3 = LDT(3, gb);
    COMPUTE(2 * g2, xa_, ta0, ta1, ta2, ta3);
    // prefetch next even group into A (g=32 on last iter: OOB-safe reads —
    // xaP overflow lands in wB region; tile pad covers row 15)
    int gc = gb + 1;
    xa_ = xaRow[(size_t)gc * NN];
    ta0 = LDT(0, gc); ta1 = LDT(1, gc); ta2 = LDT(2, gc); ta3 = LDT(3, gc);
    COMPUTE(gb, xb_, tb0, tb1, tb2, tb3);
  }

  float* ps = &part[((size_t)(s * OF) + ow) * NN + n];
  ps[0 * NN] = acc0;
  ps[1 * NN] = acc1;
  ps[2 * NN] = acc2;
  ps[3 * NN] = acc3;
#undef COMPUTE
#undef LDT
}

__global__ __launch_bounds__(256) void reduce_kernel(
    const float* __restrict__ part, const float* __restrict__ bias,
    float* __restrict__ out) {
  int gid = blockIdx.x * 256 + (int)threadIdx.x;   // 65536
  int n = gid & (NN - 1), o = gid >> 7;
  float sum = bias[o];
  #pragma unroll
  for (int c = 0; c < KS; ++c) sum += part[((size_t)c * OF + o) * NN + n];
  out[n * OF + o] = sum;
}

extern "C" void kernel_launch(void* const* d_in, const int* in_sizes, int n_in,
                              void* d_out, int out_size, void* d_ws, size_t ws_size,
                              hipStream_t stream) {
  const float* x    = (const float*)d_in[0];
  const float* w    = (const float*)d_in[1];
  const float* bias = (const float*)d_in[2];
  float* out = (float*)d_out;
  char* ws = (char*)d_ws;
  uint2* xaP2  = (uint2*)(ws);
  uint4* xaP   = (uint4*)(ws);
  uint2* wB    = (uint2*)(ws + 1048576);
  float* lxT   = (float*)(ws + 5242880);
  float* lw    = (float*)(ws + 5259264);
  float* emaxT = (float*)(ws + 5324800);
  float* part  = (float*)(ws + 5580800);

  prep_kernel<<<2560, 256, 0, stream>>>(x, w, xaP2, wB, lxT, lw);
  emax_kernel<<<256, 256, 0, stream>>>(lxT, lw, emaxT);
  main_kernel<<<1024, 256, 0, stream>>>(xaP, wB, lxT, lw, emaxT, part);
  reduce_kernel<<<256, 256, 0, stream>>>(part, bias, out);
}